// Round 4
// baseline (382.642 us; speedup 1.0000x reference)
//
#include <hip/hip_runtime.h>
#include <stdint.h>

// HalutMatmul forward, fp32 in/out, gfx950.
// N=32768, D=512, C=64, K=16, M=512, DEPTH=4, NODES=15.
// k0a: A -> At hi/lo bf16 planes (ADJACENT in ws: Atl = Ath + 131072 elems)
// k0b: L -> bf16 plane
// k1 : P = I@A (hi/lo split bf16 MFMA, 3 passes) + greedy tree codes + near-tie flags
//      tile 128x64, 4 blocks/CU (LDS 34.8KB), grid 1024
// k1b: fp64 rescue of flagged (n,c) codes
// k2 : out = onehot(codes) @ L^T via bf16 MFMA, BK=128 (64 MFMA/barrier), fp32 out

#define DDIM 512
#define CD4 256
#define CKDIM 1024
#define MOUT 512
#define NODES 15
#define CAP (1u << 20)

typedef unsigned short u16;
typedef unsigned int u32;
typedef __attribute__((ext_vector_type(8))) __bf16 bf16x8;
typedef __attribute__((ext_vector_type(4))) float f32x4;
typedef __attribute__((ext_vector_type(4))) u32 u32x4;

__device__ __forceinline__ void gld_lds16(const void* g, void* l) {
  __builtin_amdgcn_global_load_lds(
      (const __attribute__((address_space(1))) void*)g,
      (__attribute__((address_space(3))) void*)l, 16, 0, 0);
}
__device__ __forceinline__ float bf2f(u16 u) {
  uint32_t x = ((uint32_t)u) << 16; return __builtin_bit_cast(float, x);
}
__device__ __forceinline__ u16 f2bf(float f) {  // RNE
  uint32_t x = __builtin_bit_cast(uint32_t, f);
  return (u16)((x + 0x7FFFu + ((x >> 16) & 1u)) >> 16);
}

// ---- k0a: A (512x256 f32) -> At hi/lo bf16 planes (256x512 each) ----
__global__ void k0_aplanes(const float* __restrict__ Ag,
                           u16* __restrict__ Ath, u16* __restrict__ Atl) {
  int c4 = blockIdx.x;
  for (int k = threadIdx.x; k < DDIM; k += 256) {
    float x = Ag[k * CD4 + c4];
    u16 h = f2bf(x);
    u16 l = f2bf(x - bf2f(h));
    Ath[c4 * DDIM + k] = h;
    Atl[c4 * DDIM + k] = l;
  }
}

// ---- k0b: L (512x1024 f32) -> bf16 plane ----
__global__ void k0_lbf(const float* __restrict__ Lg, u16* __restrict__ Lb) {
  int i = (blockIdx.x * 256 + threadIdx.x) * 4;
  f32x4 v = *(const f32x4*)(Lg + i);
  u32 lo = (u32)f2bf(v[0]) | ((u32)f2bf(v[1]) << 16);
  u32 hi = (u32)f2bf(v[2]) | ((u32)f2bf(v[3]) << 16);
  *(u32*)(Lb + i) = lo;
  *(u32*)(Lb + i + 2) = hi;
}

// ---- k1: coarse P (hi/lo split MFMA) + tree codes + flags ----
// tile 128 rows x 64 P-cols (16 codebooks). grid (4, 256) = 1024 blocks.
// LDS union: staging If 16KB + Bt 8KB = 24KB; epilogue Pl [128][68] f32 = 34.8KB
// Ath arg must have Atl at Ath + 256*DDIM (adjacent planes in ws).
__global__ __launch_bounds__(256, 4) void k1_p_codes(
    const float* __restrict__ Ig, const u16* __restrict__ Ath,
    const float* __restrict__ Tg,
    uint8_t* __restrict__ codes, u32* __restrict__ flagcnt,
    u32* __restrict__ flaglist) {
  __shared__ __align__(16) char smem[128 * 68 * 4];
  float* If = (float*)smem;        // 16KB: I f32 tile [128 rows][8 chunks], XOR swizzle
  u16* Bt = (u16*)(smem + 16384);  // 8KB: [64 rows][8 chunks]; g<4 hi plane, g>=4 lo
  float* Pl = (float*)smem;        // 34.8KB epilogue [128][68]

  const int t = threadIdx.x, cb = blockIdx.x, nb = blockIdx.y;
  const int lane = t & 63, wave = t >> 6, quad = lane >> 4, l16 = lane & 15;
  const int wr = wave >> 1, wc = wave & 1;  // 2x2 waves over 128x64

  f32x4 acc[4][2] = {};

  for (int kb = 0; kb < 16; ++kb) {
    __syncthreads();
    // I tile: slot r*8+s holds global col-group s^(r&7). 1024 chunks = 4*256.
#pragma unroll
    for (int q = 0; q < 4; ++q) {
      int cid = t + q * 256, r = cid >> 3, s = cid & 7, g = s ^ (r & 7);
      gld_lds16(Ig + (size_t)(nb * 128 + r) * DDIM + kb * 32 + g * 4, If + cid * 4);
    }
    // B tile: 64 rows x 8 chunks = 512 chunks = 2*256 (R3 bug: was 1*256).
    // global chunk g: g<4 -> hi plane, g>=4 -> lo plane (Atl = Ath + 256*DDIM)
#pragma unroll
    for (int q = 0; q < 2; ++q) {
      int cid = t + q * 256, r = cid >> 3, s = cid & 7, g = s ^ (r & 7);
      gld_lds16(Ath + (size_t)(g >> 2) * (256 * DDIM) +
                    (size_t)(cb * 64 + r) * DDIM + kb * 32 + (g & 3) * 8,
                Bt + cid * 8);
    }
    __syncthreads();

    bf16x8 ah[4], al[4], bh[2], bl[2];
#pragma unroll
    for (int i = 0; i < 4; ++i) {
      int ra = wr * 64 + i * 16 + l16;
      int s0 = ra * 8 + ((quad * 2) ^ (ra & 7));
      int s1 = ra * 8 + ((quad * 2 + 1) ^ (ra & 7));
      f32x4 c0 = *(const f32x4*)(If + s0 * 4);
      f32x4 c1 = *(const f32x4*)(If + s1 * 4);
      float xs[8] = {c0[0], c0[1], c0[2], c0[3], c1[0], c1[1], c1[2], c1[3]};
      u32 hw[4], lw[4];
#pragma unroll
      for (int p = 0; p < 4; ++p) {  // truncation split: hi = top16 bits, lo = x - hi
        u32 u0 = __builtin_bit_cast(u32, xs[2 * p]);
        u32 u1 = __builtin_bit_cast(u32, xs[2 * p + 1]);
        hw[p] = __builtin_amdgcn_perm(u1, u0, 0x07060302);
        float h0 = __builtin_bit_cast(float, u0 & 0xFFFF0000u);
        float h1 = __builtin_bit_cast(float, u1 & 0xFFFF0000u);
        u32 l0 = __builtin_bit_cast(u32, xs[2 * p] - h0);
        u32 l1 = __builtin_bit_cast(u32, xs[2 * p + 1] - h1);
        lw[p] = __builtin_amdgcn_perm(l1, l0, 0x07060302);
      }
      ah[i] = __builtin_bit_cast(bf16x8, (u32x4){hw[0], hw[1], hw[2], hw[3]});
      al[i] = __builtin_bit_cast(bf16x8, (u32x4){lw[0], lw[1], lw[2], lw[3]});
    }
#pragma unroll
    for (int j = 0; j < 2; ++j) {
      int rb = wc * 32 + j * 16 + l16;
      int sh = quad ^ (rb & 7), sl = (4 + quad) ^ (rb & 7);
      bh[j] = *(const bf16x8*)(Bt + rb * 64 + sh * 8);
      bl[j] = *(const bf16x8*)(Bt + rb * 64 + sl * 8);
    }
#pragma unroll
    for (int i = 0; i < 4; ++i)
#pragma unroll
      for (int j = 0; j < 2; ++j) {
        acc[i][j] = __builtin_amdgcn_mfma_f32_16x16x32_bf16(ah[i], bh[j], acc[i][j], 0, 0, 0);
        acc[i][j] = __builtin_amdgcn_mfma_f32_16x16x32_bf16(ah[i], bl[j], acc[i][j], 0, 0, 0);
        acc[i][j] = __builtin_amdgcn_mfma_f32_16x16x32_bf16(al[i], bh[j], acc[i][j], 0, 0, 0);
      }
  }

  __syncthreads();
  // C/D: col = lane&15, row = quad*4 + r. Pl stride 68 breaks bank aliasing.
#pragma unroll
  for (int i = 0; i < 4; ++i)
#pragma unroll
    for (int j = 0; j < 2; ++j)
#pragma unroll
      for (int r = 0; r < 4; ++r) {
        int row = wr * 64 + i * 16 + quad * 4 + r;
        int col = wc * 32 + j * 16 + l16;
        Pl[row * 68 + col] = acc[i][j][r];
      }
  __syncthreads();

  // tree descent: 128 rows x 16 codebooks = 2048, 8 per thread; flag near-ties
  for (int it = 0; it < 8; ++it) {
    int idx = it * 256 + t, n = idx >> 4, cl = idx & 15;
    f32x4 pv = *(const f32x4*)(Pl + n * 68 + cl * 4);
    int cg = cb * 16 + cl;
    const float* Tc = Tg + cg * NODES;
    int node = 0, k = 0;
    float mm = 1e30f;
#pragma unroll
    for (int l = 0; l < 4; ++l) {
      float h = pv[l] - Tc[node];
      mm = fminf(mm, __builtin_fabsf(h));
      int bit = h > 0.0f ? 1 : 0;
      k = (k << 1) | bit;
      node = 2 * node + 1 + bit;
    }
    int ng = nb * 128 + n;
    codes[(size_t)ng * 64 + cg] = (uint8_t)k;
    if (mm < 2e-3f) {  // coarse error ~1e-4 << tau: unflagged codes are exact
      u32 pos = atomicAdd(flagcnt, 1u);
      if (pos < CAP) flaglist[pos] = ((u32)ng << 6) | (u32)cg;
    }
  }
}

// ---- k1b: fp64 rescue of flagged codes ----
__global__ void k1b_rescue(const float* __restrict__ Ig, const float* __restrict__ Ag,
                           const float* __restrict__ Tg, const u32* __restrict__ cnt,
                           const u32* __restrict__ list, uint8_t* __restrict__ codes) {
  u32 total = *cnt;
  if (total > CAP) total = CAP;
  for (u32 e = blockIdx.x * blockDim.x + threadIdx.x; e < total;
       e += gridDim.x * blockDim.x) {
    u32 v = list[e];
    int n = v >> 6, c = v & 63;
    double p[4] = {0.0, 0.0, 0.0, 0.0};
    const float* Ir = Ig + (size_t)n * DDIM;
    const float* Ac = Ag + c * 4;
    for (int d = 0; d < DDIM; ++d) {
      double iv = (double)Ir[d];
      f32x4 a = *(const f32x4*)(Ac + (size_t)d * CD4);
      p[0] += iv * (double)a[0]; p[1] += iv * (double)a[1];
      p[2] += iv * (double)a[2]; p[3] += iv * (double)a[3];
    }
    const float* Tc = Tg + c * NODES;
    int node = 0, k = 0;
    for (int l = 0; l < 4; ++l) {
      int bit = p[l] > (double)Tc[node] ? 1 : 0;
      k = (k << 1) | bit;
      node = 2 * node + 1 + bit;
    }
    codes[(size_t)n * 64 + c] = (uint8_t)k;
  }
}

// ---- k2: out = onehot(codes) @ L^T, fp32 out. BK=128. ----
// grid (4, 256): x = m-col block, y = n-row block. LDS 40.6KB -> 3 blocks/CU.
__global__ __launch_bounds__(256, 3) void k2_out(
    const uint8_t* __restrict__ codes, const u16* __restrict__ Lb,
    float* __restrict__ Og) {
  __shared__ __align__(16) u16 Ltile[128 * 128];      // 32KB [m-row][16 chunks], XOR
  __shared__ __align__(16) uint8_t codesT[64 * 128];  // [c][n] 8KB
  __shared__ __align__(16) u16 lut[32 * 8];

  const int t = threadIdx.x, mb = blockIdx.x, nb = blockIdx.y;
  const int lane = t & 63, wave = t >> 6, quad = lane >> 4, l16 = lane & 15;
  const int wr = wave >> 1, wc = wave & 1;

  if (t < 32) {  // A-frag LUT: entry (h,v): frag[j] = (v == h*8+j)
    int h = t >> 4, v = t & 15;
#pragma unroll
    for (int j = 0; j < 8; ++j)
      lut[t * 8 + j] = (v == h * 8 + j) ? (u16)0x3F80 : (u16)0;
  }
  {  // codes -> [c][n] transposed in LDS
    int n = t >> 1, part = t & 1;
    const u32* src = (const u32*)(codes + (size_t)(nb * 128 + n) * 64 + part * 32);
#pragma unroll
    for (int i = 0; i < 8; ++i) {
      u32 w = src[i];
      int c4 = part * 32 + i * 4;
      codesT[(c4 + 0) * 128 + n] = (uint8_t)(w & 0xff);
      codesT[(c4 + 1) * 128 + n] = (uint8_t)((w >> 8) & 0xff);
      codesT[(c4 + 2) * 128 + n] = (uint8_t)((w >> 16) & 0xff);
      codesT[(c4 + 3) * 128 + n] = (uint8_t)((w >> 24) & 0xff);
    }
  }

  f32x4 acc[4][4] = {};

  for (int kb = 0; kb < 8; ++kb) {
    __syncthreads();
    // L tile: 128 rows x 16 chunks = 2048 = 8*256; slot s holds g = s^(r&15)
#pragma unroll
    for (int q = 0; q < 8; ++q) {
      int cid = t + q * 256, r = cid >> 4, s = cid & 15, g = s ^ (r & 15);
      gld_lds16(Lb + (size_t)(mb * 128 + r) * CKDIM + kb * 128 + g * 8,
                Ltile + cid * 8);
    }
    __syncthreads();

#pragma unroll
    for (int ks = 0; ks < 4; ++ks) {
      // ck = kb*128 + ks*32 + quad*8 + j  ->  codebook, leaf-half
      const int c0 = kb * 8 + ks * 2 + (quad >> 1);
      const int h = quad & 1;
      bf16x8 a[4], b[4];
#pragma unroll
      for (int i = 0; i < 4; ++i) {
        int row = wr * 64 + i * 16 + l16;
        int v = codesT[c0 * 128 + row] & 15;  // defensive mask
        a[i] = *(const bf16x8*)(lut + (h * 16 + v) * 8);
      }
#pragma unroll
      for (int j = 0; j < 4; ++j) {
        int rm = wc * 64 + j * 16 + l16;
        int slot = (ks * 4 + quad) ^ (rm & 15);
        b[j] = *(const bf16x8*)(Ltile + rm * 128 + slot * 8);
      }
#pragma unroll
      for (int i = 0; i < 4; ++i)
#pragma unroll
        for (int j = 0; j < 4; ++j)
          acc[i][j] = __builtin_amdgcn_mfma_f32_16x16x32_bf16(a[i], b[j], acc[i][j], 0, 0, 0);
    }
  }

#pragma unroll
  for (int i = 0; i < 4; ++i)
#pragma unroll
    for (int j = 0; j < 4; ++j) {
      int row = nb * 128 + wr * 64 + i * 16 + quad * 4;
      int col = mb * 128 + wc * 64 + j * 16 + l16;
#pragma unroll
      for (int r = 0; r < 4; ++r)
        Og[(size_t)(row + r) * MOUT + col] = acc[i][j][r];
    }
}

extern "C" void kernel_launch(void* const* d_in, const int* in_sizes, int n_in,
                              void* d_out, int out_size, void* d_ws, size_t ws_size,
                              hipStream_t stream) {
  // inputs (all float32): I (N,512), T (960), L (512,64,16), A (512,256), S, B
  const float* Ig = (const float*)d_in[0];
  const float* Tg = (const float*)d_in[1];
  const float* Lg = (const float*)d_in[2];
  const float* Ag = (const float*)d_in[3];
  float* Og = (float*)d_out;

  char* ws = (char*)d_ws;
  u32* cnt = (u32*)ws;                                 // 4B @ 0
  u32* list = (u32*)(ws + 4096);                       // 4MB flag list
  uint8_t* codes = (uint8_t*)(ws + (8u << 20));        // 2MB @ 8MB
  u16* Ath = (u16*)(ws + (10u << 20));                 // 256KB @ 10MB
  u16* Atl = Ath + 256 * DDIM;                         // 256KB, ADJACENT (k1 relies on it)
  u16* Lbf = (u16*)(ws + (10u << 20) + (512u << 10));  // 1MB

  hipMemsetAsync(cnt, 0, 4, stream);
  k0_aplanes<<<dim3(256), dim3(256), 0, stream>>>(Ag, Ath, Atl);
  k0_lbf<<<dim3(512), dim3(256), 0, stream>>>(Lg, Lbf);
  k1_p_codes<<<dim3(4, 256), dim3(256), 0, stream>>>(Ig, Ath, Tg, codes, cnt, list);
  k1b_rescue<<<dim3(256), dim3(256), 0, stream>>>(Ig, Ag, Tg, cnt, list, codes);
  k2_out<<<dim3(4, 256), dim3(256), 0, stream>>>(codes, Lbf, Og);
}

// Round 5
// 378.756 us; speedup vs baseline: 1.0103x; 1.0103x over previous
//
#include <hip/hip_runtime.h>
#include <stdint.h>

// HalutMatmul forward, fp32 in/out, gfx950.
// N=32768, D=512, C=64, K=16, M=512, DEPTH=4, NODES=15.
// k0a: A -> At hi/lo bf16 planes via LDS-tiled transpose (ADJACENT: Atl = Ath + 256*512)
// k0b: L -> bf16 plane
// k1 : P = I@A (hi/lo split bf16 MFMA, 3 passes) + greedy tree codes + near-tie flags
//      tile 64 rows x 256 cols (ALL codebooks -> I fetched from HBM exactly once),
//      grid 512, 2 blocks/CU (LDS 64KB union), 48 MFMA/wave-iter
// k1b: fp64 rescue of flagged (n,c) codes
// k2 : out = onehot(codes) @ L^T via bf16 MFMA, BK=128, fp32 out (unchanged from R4)

#define DDIM 512
#define CD4 256
#define CKDIM 1024
#define MOUT 512
#define NODES 15
#define CAP (1u << 20)

typedef unsigned short u16;
typedef unsigned int u32;
typedef __attribute__((ext_vector_type(8))) __bf16 bf16x8;
typedef __attribute__((ext_vector_type(4))) float f32x4;
typedef __attribute__((ext_vector_type(4))) u32 u32x4;

__device__ __forceinline__ void gld_lds16(const void* g, void* l) {
  __builtin_amdgcn_global_load_lds(
      (const __attribute__((address_space(1))) void*)g,
      (__attribute__((address_space(3))) void*)l, 16, 0, 0);
}
__device__ __forceinline__ float bf2f(u16 u) {
  uint32_t x = ((uint32_t)u) << 16; return __builtin_bit_cast(float, x);
}
__device__ __forceinline__ u16 f2bf(float f) {  // RNE
  uint32_t x = __builtin_bit_cast(uint32_t, f);
  return (u16)((x + 0x7FFFu + ((x >> 16) & 1u)) >> 16);
}

// ---- k0a: A (512x256 f32) -> At hi/lo bf16 planes (256x512 each), tiled ----
// grid (4, 8): 64x64 tiles. Coalesced reads AND writes via LDS transpose.
__global__ __launch_bounds__(256) void k0_aplanes(const float* __restrict__ Ag,
                                                  u16* __restrict__ Ath,
                                                  u16* __restrict__ Atl) {
  __shared__ float Tl[64][65];  // +1 pad: conflict-free column reads
  const int t = threadIdx.x, cx = blockIdx.x, ky = blockIdx.y;
  const int lane = t & 63, w = t >> 6;
#pragma unroll
  for (int rr = 0; rr < 16; ++rr) {  // read: rows coalesced over lanes
    int r = w * 16 + rr;
    Tl[r][lane] = Ag[(size_t)(ky * 64 + r) * CD4 + cx * 64 + lane];
  }
  __syncthreads();
#pragma unroll
  for (int rr = 0; rr < 16; ++rr) {  // write: k coalesced over lanes
    int c = w * 16 + rr;             // local c4
    float x = Tl[lane][c];
    u16 h = f2bf(x);
    u16 l = f2bf(x - bf2f(h));
    size_t o = (size_t)(cx * 64 + c) * DDIM + ky * 64 + lane;
    Ath[o] = h;
    Atl[o] = l;
  }
}

// ---- k0b: L (512x1024 f32) -> bf16 plane ----
__global__ void k0_lbf(const float* __restrict__ Lg, u16* __restrict__ Lb) {
  int i = (blockIdx.x * 256 + threadIdx.x) * 4;
  f32x4 v = *(const f32x4*)(Lg + i);
  u32 lo = (u32)f2bf(v[0]) | ((u32)f2bf(v[1]) << 16);
  u32 hi = (u32)f2bf(v[2]) | ((u32)f2bf(v[3]) << 16);
  *(u32*)(Lb + i) = lo;
  *(u32*)(Lb + i + 2) = hi;
}

// ---- k1: coarse P (hi/lo split MFMA) + tree codes + flags ----
// tile 64 I-rows x 256 P-cols (all 64 codebooks). grid 512 (nb only).
// LDS union 64KB: staging If 8KB + Bt 32KB; epilogue Pl[64][256] f32 (XOR swizzle).
// Ath arg must have Atl at Ath + 256*DDIM (adjacent planes in ws).
__global__ __launch_bounds__(256, 2) void k1_p_codes(
    const float* __restrict__ Ig, const u16* __restrict__ Ath,
    const float* __restrict__ Tg,
    uint8_t* __restrict__ codes, u32* __restrict__ flagcnt,
    u32* __restrict__ flaglist) {
  __shared__ __align__(16) char smem[65536];
  float* If = (float*)smem;        // 8KB: [64 rows][8 slots]x16B, slot s holds g=s^(r&7)
  u16* Bt = (u16*)(smem + 8192);   // 32KB: [256 rows][8 slots]; g<4 hi plane, g>=4 lo
  float* Pl = (float*)smem;        // 64KB epilogue [64][256], col ^ ((row&12)<<2)

  const int t = threadIdx.x, nb = blockIdx.x;
  const int lane = t & 63, wave = t >> 6, quad = lane >> 4, l16 = lane & 15;
  const int wr = wave >> 1, wc = wave & 1;  // 2x2 waves over 64x256

  f32x4 acc[2][8] = {};

  for (int kb = 0; kb < 16; ++kb) {
    __syncthreads();
    // I tile: 64 rows x 8 chunk-slots = 512 chunks = 2*256
#pragma unroll
    for (int q = 0; q < 2; ++q) {
      int cid = t + q * 256, r = cid >> 3, s = cid & 7, g = s ^ (r & 7);
      gld_lds16(Ig + (size_t)(nb * 64 + r) * DDIM + kb * 32 + g * 4, If + cid * 4);
    }
    // B tile: 256 At-rows x 8 slots = 2048 chunks = 8*256.
    // global chunk g: g<4 -> hi plane (k-chunk g), g>=4 -> lo plane (k-chunk g-4)
#pragma unroll
    for (int q = 0; q < 8; ++q) {
      int cid = t + q * 256, r = cid >> 3, s = cid & 7, g = s ^ (r & 7);
      gld_lds16(Ath + (size_t)(g >> 2) * (256 * DDIM) +
                    (size_t)r * DDIM + kb * 32 + (g & 3) * 8,
                Bt + cid * 8);
    }
    __syncthreads();

    bf16x8 ah[2], al[2], bh[8], bl[8];
#pragma unroll
    for (int i = 0; i < 2; ++i) {
      int ra = wr * 32 + i * 16 + l16;
      int s0 = ra * 8 + ((quad * 2) ^ (ra & 7));
      int s1 = ra * 8 + ((quad * 2 + 1) ^ (ra & 7));
      f32x4 c0 = *(const f32x4*)(If + s0 * 4);
      f32x4 c1 = *(const f32x4*)(If + s1 * 4);
      float xs[8] = {c0[0], c0[1], c0[2], c0[3], c1[0], c1[1], c1[2], c1[3]};
      u32 hw[4], lw[4];
#pragma unroll
      for (int p = 0; p < 4; ++p) {  // truncation split: hi = top16 bits, lo = x - hi
        u32 u0 = __builtin_bit_cast(u32, xs[2 * p]);
        u32 u1 = __builtin_bit_cast(u32, xs[2 * p + 1]);
        hw[p] = __builtin_amdgcn_perm(u1, u0, 0x07060302);
        float h0 = __builtin_bit_cast(float, u0 & 0xFFFF0000u);
        float h1 = __builtin_bit_cast(float, u1 & 0xFFFF0000u);
        u32 l0 = __builtin_bit_cast(u32, xs[2 * p] - h0);
        u32 l1 = __builtin_bit_cast(u32, xs[2 * p + 1] - h1);
        lw[p] = __builtin_amdgcn_perm(l1, l0, 0x07060302);
      }
      ah[i] = __builtin_bit_cast(bf16x8, (u32x4){hw[0], hw[1], hw[2], hw[3]});
      al[i] = __builtin_bit_cast(bf16x8, (u32x4){lw[0], lw[1], lw[2], lw[3]});
    }
#pragma unroll
    for (int j = 0; j < 8; ++j) {
      int rb = wc * 128 + j * 16 + l16;
      int sh = quad ^ (rb & 7), sl = (4 + quad) ^ (rb & 7);
      bh[j] = *(const bf16x8*)(Bt + (rb * 8 + sh) * 8);
      bl[j] = *(const bf16x8*)(Bt + (rb * 8 + sl) * 8);
    }
#pragma unroll
    for (int i = 0; i < 2; ++i)
#pragma unroll
      for (int j = 0; j < 8; ++j) {
        acc[i][j] = __builtin_amdgcn_mfma_f32_16x16x32_bf16(ah[i], bh[j], acc[i][j], 0, 0, 0);
        acc[i][j] = __builtin_amdgcn_mfma_f32_16x16x32_bf16(ah[i], bl[j], acc[i][j], 0, 0, 0);
        acc[i][j] = __builtin_amdgcn_mfma_f32_16x16x32_bf16(al[i], bh[j], acc[i][j], 0, 0, 0);
      }
  }

  __syncthreads();
  // C/D: col = lane&15, row = quad*4 + r. Swizzle: col ^ ((row&12)<<2)
  // (quads {0,2}/{1,3} pair on banks -> 2-way, free).
#pragma unroll
  for (int i = 0; i < 2; ++i)
#pragma unroll
    for (int j = 0; j < 8; ++j)
#pragma unroll
      for (int r = 0; r < 4; ++r) {
        int row = wr * 32 + i * 16 + quad * 4 + r;
        int col = wc * 128 + j * 16 + l16;
        Pl[row * 256 + (col ^ ((row & 12) << 2))] = acc[i][j][r];
      }
  __syncthreads();

  // tree descent: 64 rows x 64 codebooks = 4096 codes, 16 per thread
  for (int it = 0; it < 16; ++it) {
    int idx = it * 256 + t, n = idx >> 6, cg = idx & 63;
    f32x4 pv = *(const f32x4*)(Pl + n * 256 + ((cg * 4) ^ ((n & 12) << 2)));
    const float* Tc = Tg + cg * NODES;
    int node = 0, k = 0;
    float mm = 1e30f;
#pragma unroll
    for (int l = 0; l < 4; ++l) {
      float h = pv[l] - Tc[node];
      mm = fminf(mm, __builtin_fabsf(h));
      int bit = h > 0.0f ? 1 : 0;
      k = (k << 1) | bit;
      node = 2 * node + 1 + bit;
    }
    int ng = nb * 64 + n;
    codes[(size_t)ng * 64 + cg] = (uint8_t)k;
    if (mm < 2e-3f) {  // coarse error ~1e-4 << tau: unflagged codes are exact
      u32 pos = atomicAdd(flagcnt, 1u);
      if (pos < CAP) flaglist[pos] = ((u32)ng << 6) | (u32)cg;
    }
  }
}

// ---- k1b: fp64 rescue of flagged codes ----
__global__ void k1b_rescue(const float* __restrict__ Ig, const float* __restrict__ Ag,
                           const float* __restrict__ Tg, const u32* __restrict__ cnt,
                           const u32* __restrict__ list, uint8_t* __restrict__ codes) {
  u32 total = *cnt;
  if (total > CAP) total = CAP;
  for (u32 e = blockIdx.x * blockDim.x + threadIdx.x; e < total;
       e += gridDim.x * blockDim.x) {
    u32 v = list[e];
    int n = v >> 6, c = v & 63;
    double p[4] = {0.0, 0.0, 0.0, 0.0};
    const float* Ir = Ig + (size_t)n * DDIM;
    const float* Ac = Ag + c * 4;
    for (int d = 0; d < DDIM; ++d) {
      double iv = (double)Ir[d];
      f32x4 a = *(const f32x4*)(Ac + (size_t)d * CD4);
      p[0] += iv * (double)a[0]; p[1] += iv * (double)a[1];
      p[2] += iv * (double)a[2]; p[3] += iv * (double)a[3];
    }
    const float* Tc = Tg + c * NODES;
    int node = 0, k = 0;
    for (int l = 0; l < 4; ++l) {
      int bit = p[l] > (double)Tc[node] ? 1 : 0;
      k = (k << 1) | bit;
      node = 2 * node + 1 + bit;
    }
    codes[(size_t)n * 64 + c] = (uint8_t)k;
  }
}

// ---- k2: out = onehot(codes) @ L^T, fp32 out. BK=128. (unchanged from R4) ----
__global__ __launch_bounds__(256, 3) void k2_out(
    const uint8_t* __restrict__ codes, const u16* __restrict__ Lb,
    float* __restrict__ Og) {
  __shared__ __align__(16) u16 Ltile[128 * 128];      // 32KB [m-row][16 chunks], XOR
  __shared__ __align__(16) uint8_t codesT[64 * 128];  // [c][n] 8KB
  __shared__ __align__(16) u16 lut[32 * 8];

  const int t = threadIdx.x, mb = blockIdx.x, nb = blockIdx.y;
  const int lane = t & 63, wave = t >> 6, quad = lane >> 4, l16 = lane & 15;
  const int wr = wave >> 1, wc = wave & 1;

  if (t < 32) {  // A-frag LUT: entry (h,v): frag[j] = (v == h*8+j)
    int h = t >> 4, v = t & 15;
#pragma unroll
    for (int j = 0; j < 8; ++j)
      lut[t * 8 + j] = (v == h * 8 + j) ? (u16)0x3F80 : (u16)0;
  }
  {  // codes -> [c][n] transposed in LDS
    int n = t >> 1, part = t & 1;
    const u32* src = (const u32*)(codes + (size_t)(nb * 128 + n) * 64 + part * 32);
#pragma unroll
    for (int i = 0; i < 8; ++i) {
      u32 w = src[i];
      int c4 = part * 32 + i * 4;
      codesT[(c4 + 0) * 128 + n] = (uint8_t)(w & 0xff);
      codesT[(c4 + 1) * 128 + n] = (uint8_t)((w >> 8) & 0xff);
      codesT[(c4 + 2) * 128 + n] = (uint8_t)((w >> 16) & 0xff);
      codesT[(c4 + 3) * 128 + n] = (uint8_t)((w >> 24) & 0xff);
    }
  }

  f32x4 acc[4][4] = {};

  for (int kb = 0; kb < 8; ++kb) {
    __syncthreads();
#pragma unroll
    for (int q = 0; q < 8; ++q) {
      int cid = t + q * 256, r = cid >> 4, s = cid & 15, g = s ^ (r & 15);
      gld_lds16(Lb + (size_t)(mb * 128 + r) * CKDIM + kb * 128 + g * 8,
                Ltile + cid * 8);
    }
    __syncthreads();

#pragma unroll
    for (int ks = 0; ks < 4; ++ks) {
      const int c0 = kb * 8 + ks * 2 + (quad >> 1);
      const int h = quad & 1;
      bf16x8 a[4], b[4];
#pragma unroll
      for (int i = 0; i < 4; ++i) {
        int row = wr * 64 + i * 16 + l16;
        int v = codesT[c0 * 128 + row] & 15;  // defensive mask
        a[i] = *(const bf16x8*)(lut + (h * 16 + v) * 8);
      }
#pragma unroll
      for (int j = 0; j < 4; ++j) {
        int rm = wc * 64 + j * 16 + l16;
        int slot = (ks * 4 + quad) ^ (rm & 15);
        b[j] = *(const bf16x8*)(Ltile + rm * 128 + slot * 8);
      }
#pragma unroll
      for (int i = 0; i < 4; ++i)
#pragma unroll
        for (int j = 0; j < 4; ++j)
          acc[i][j] = __builtin_amdgcn_mfma_f32_16x16x32_bf16(a[i], b[j], acc[i][j], 0, 0, 0);
    }
  }

#pragma unroll
  for (int i = 0; i < 4; ++i)
#pragma unroll
    for (int j = 0; j < 4; ++j) {
      int row = nb * 128 + wr * 64 + i * 16 + quad * 4;
      int col = mb * 128 + wc * 64 + j * 16 + l16;
#pragma unroll
      for (int r = 0; r < 4; ++r)
        Og[(size_t)(row + r) * MOUT + col] = acc[i][j][r];
    }
}

extern "C" void kernel_launch(void* const* d_in, const int* in_sizes, int n_in,
                              void* d_out, int out_size, void* d_ws, size_t ws_size,
                              hipStream_t stream) {
  // inputs (all float32): I (N,512), T (960), L (512,64,16), A (512,256), S, B
  const float* Ig = (const float*)d_in[0];
  const float* Tg = (const float*)d_in[1];
  const float* Lg = (const float*)d_in[2];
  const float* Ag = (const float*)d_in[3];
  float* Og = (float*)d_out;

  char* ws = (char*)d_ws;
  u32* cnt = (u32*)ws;                                 // 4B @ 0
  u32* list = (u32*)(ws + 4096);                       // 4MB flag list
  uint8_t* codes = (uint8_t*)(ws + (8u << 20));        // 2MB @ 8MB
  u16* Ath = (u16*)(ws + (10u << 20));                 // 256KB @ 10MB
  u16* Atl = Ath + 256 * DDIM;                         // 256KB, ADJACENT (k1 relies on it)
  u16* Lbf = (u16*)(ws + (10u << 20) + (512u << 10));  // 1MB

  hipMemsetAsync(cnt, 0, 4, stream);
  k0_aplanes<<<dim3(4, 8), dim3(256), 0, stream>>>(Ag, Ath, Atl);
  k0_lbf<<<dim3(512), dim3(256), 0, stream>>>(Lg, Lbf);
  k1_p_codes<<<dim3(512), dim3(256), 0, stream>>>(Ig, Ath, Tg, codes, cnt, list);
  k1b_rescue<<<dim3(256), dim3(256), 0, stream>>>(Ig, Ag, Tg, cnt, list, codes);
  k2_out<<<dim3(4, 256), dim3(256), 0, stream>>>(codes, Lbf, Og);
}